// Round 6
// baseline (322.027 us; speedup 1.0000x reference)
//
#include <hip/hip_runtime.h>
#include <math.h>

#define Bsz 8
#define Nn 1024
#define CIN 256
#define COUT 256
#define NR 4
#define NH 4

typedef unsigned short u16;
typedef __attribute__((ext_vector_type(8))) short bf16x8;
typedef __attribute__((ext_vector_type(4))) float f32x4;
typedef __attribute__((ext_vector_type(2))) float f32x2;

// ws layout (bytes):
//   fTf  : [sl=r*8+b][h][jb 0..31][nt 0..3][lane] bf16x8  16 MB @ 0
//   Lip  : [combo=r*4+h][b][n] f32 (li*log2e)   512K @ 16M
//   Ljp  : same                                  512K @ 16.5M
//   adjm : [b][i][r][16] u64                     4 MB @ 17M
//   Xbf  : [b*n][k] bf16                         4 MB @ 21M
//   Wfrag: [r][cg 0..15][kc 0..7][lane][e] bf16 (A-frag order) 512K @ 25M
//   wa_l : [combo][k] f32                        16K  @ 25.5M
//   wa_r : [combo][k] f32                        16K  @ +16K
#define OFF_LIP (16u << 20)
#define OFF_LJP ((16u << 20) + (512u << 10))
#define OFF_ADJM (17u << 20)
#define OFF_XBF (21u << 20)
#define OFF_WFRAG (25u << 20)
#define OFF_WAL ((25u << 20) + (512u << 10))
#define OFF_WAR ((25u << 20) + (528u << 10))

#define LOG2E 1.4426950408889634f

__device__ __forceinline__ short f2bf(float x) {
  union { float f; unsigned u; } v; v.f = x;
  unsigned r = (v.u + 0x7FFFu + ((v.u >> 16) & 1u)) >> 16;
  return (short)r;
}

__device__ __forceinline__ float fast_exp2(float x) {
#if __has_builtin(__builtin_amdgcn_exp2f)
  return __builtin_amdgcn_exp2f(x);
#else
  return exp2f(x);
#endif
}

__device__ __forceinline__ int sbfe1(unsigned v, int bit) {
#if __has_builtin(__builtin_amdgcn_sbfe)
  return __builtin_amdgcn_sbfe((int)v, bit, 1);
#else
  return ((int)(v << (31 - bit))) >> 31;
#endif
}

__device__ __forceinline__ unsigned perm_hi16(unsigned hi, unsigned lo) {
#if __has_builtin(__builtin_amdgcn_perm)
  return __builtin_amdgcn_perm(hi, lo, 0x07060302u);
#else
  return (lo >> 16) | (hi & 0xFFFF0000u);
#endif
}

// ---------- pack (bid<32768) + prep: Wfrag (next 32) + wa tables (next 16) ----------
__global__ __launch_bounds__(256, 4)
void gatt_packprep(const int4* __restrict__ adj4, const float* __restrict__ W,
                   const float* __restrict__ a, unsigned long long* __restrict__ adjm,
                   u16* __restrict__ Wfrag, float* __restrict__ wa_l,
                   float* __restrict__ wa_r) {
  const int t = threadIdx.x;
  if (blockIdx.x < 32768) {
    const int wid = blockIdx.x * 4 + (t >> 6);
    const int lane = t & 63;
    const int jw = wid & 15;
    const int i = (wid >> 4) & 1023;
    const int b = wid >> 14;
    const int j = jw * 64 + lane;
    const int4 av = adj4[(size_t)(b * Nn + i) * Nn + j];
    const unsigned long long b0 = __ballot(av.x != 0);
    const unsigned long long b1 = __ballot(av.y != 0);
    const unsigned long long b2 = __ballot(av.z != 0);
    const unsigned long long b3 = __ballot(av.w != 0);
    if (lane < 4) {
      unsigned long long v = (lane == 0) ? b0 : (lane == 1) ? b1 : (lane == 2) ? b2 : b3;
      adjm[((size_t)((b * Nn + i) * NR + lane)) * 16 + jw] = v;
    }
  } else if (blockIdx.x < 32768 + 32) {
    // W -> bf16 in MFMA A-frag order: Wfrag[r][(cg*8+kc)*512 + (quad*16+m)*8 + e]
    const int bid2 = blockIdx.x - 32768;
    const int r = bid2 >> 3, kc = bid2 & 7;
    const int cg = t >> 4, mm = t & 15;
    float wv[32];
#pragma unroll 8
    for (int kk = 0; kk < 32; ++kk)
      wv[kk] = W[(size_t)r * 65536 + (size_t)(kc * 32 + kk) * COUT + t];
    u16* base = Wfrag + (size_t)r * 65536 + (size_t)(cg * 8 + kc) * 512 + mm * 8;
#pragma unroll
    for (int quad = 0; quad < 4; ++quad) {
      u16 pk[8];
#pragma unroll
      for (int e = 0; e < 8; ++e) pk[e] = (u16)f2bf(wv[quad * 8 + e]);
      *(int4*)(base + quad * 128) = *(int4*)pk;
    }
  } else {
    const int cb = blockIdx.x - 32768 - 32;
    const int r = cb >> 2, h = cb & 3;
    float sl = 0.f, sr = 0.f;
    const float* Wp = W + (size_t)r * 65536 + (size_t)t * COUT + h * 64;
    const float* ap = a + r * 512 + h * 128;
#pragma unroll 8
    for (int c = 0; c < 64; ++c) {
      const float wv = Wp[c];
      sl = fmaf(wv, ap[c], sl);
      sr = fmaf(wv, ap[64 + c], sr);
    }
    wa_l[(size_t)cb * CIN + t] = sl;
    wa_r[(size_t)cb * CIN + t] = sr;
  }
}

// ---------- logits (fp32, pre-scaled by log2e) + X->bf16 conversion ----------
__global__ __launch_bounds__(256, 4)
void gatt_logitx(const float* __restrict__ X, const float4* __restrict__ wal4,
                 const float4* __restrict__ war4, float* __restrict__ Lip,
                 float* __restrict__ Ljp, u16* __restrict__ Xbf) {
  __shared__ float Xs[16 * 260];
  const int t = threadIdx.x;
  const int row0 = blockIdx.x * 16;
  {
    const int il = t >> 4, kq = t & 15;
    const float4* xp = (const float4*)(X + (size_t)(row0 + il) * CIN + kq * 16);
    float4 v[4];
    u16 pk[16];
#pragma unroll
    for (int u = 0; u < 4; ++u) {
      v[u] = xp[u];
      pk[u * 4 + 0] = (u16)f2bf(v[u].x);
      pk[u * 4 + 1] = (u16)f2bf(v[u].y);
      pk[u * 4 + 2] = (u16)f2bf(v[u].z);
      pk[u * 4 + 3] = (u16)f2bf(v[u].w);
    }
    float4* dst = (float4*)(Xs + il * 260 + kq * 16);
#pragma unroll
    for (int u = 0; u < 4; ++u) dst[u] = v[u];
    u16* xb = Xbf + (size_t)(row0 + il) * CIN + kq * 16;
    *(int4*)xb = *(int4*)pk;
    *(int4*)(xb + 8) = *(int4*)(pk + 8);
  }
  __syncthreads();
  const int rl = t >> 4, combo = t & 15;
  float li = 0.f, lj = 0.f;
#pragma unroll 8
  for (int k4 = 0; k4 < 64; ++k4) {
    const float4 x4 = *(const float4*)(Xs + rl * 260 + k4 * 4);
    const float4 wl = wal4[combo * 64 + k4];
    const float4 wr = war4[combo * 64 + k4];
    li += x4.x * wl.x + x4.y * wl.y + x4.z * wl.z + x4.w * wl.w;
    lj += x4.x * wr.x + x4.y * wr.y + x4.z * wr.z + x4.w * wr.w;
  }
  const int g = row0 + rl, b = g >> 10, n = g & 1023;
  const size_t idx = ((size_t)(combo * Bsz + b)) * Nn + n;
  Lip[idx] = li * LOG2E;
  Ljp[idx] = lj * LOG2E;
}

// ---------- f GEMM: zero-LDS, zero-barrier MFMA streaming ----------
// grid 1024: bid&3=r, (bid>>2)&7=b, bid>>5=ntl (32 n). block 256 = 4 waves,
// wave = c-quarter (= head). A-frags from Wfrag (wave-contiguous 1KB, L2-hot);
// B-frags direct from Xbf (lane m->row n, quad->k: 16 full 64B lines/wave).
__global__ __launch_bounds__(256, 4)
void gatt_fgemm(const u16* __restrict__ Xbf, const u16* __restrict__ Wfrag,
                u16* __restrict__ fTf) {
  const int t = threadIdx.x;
  const int r = blockIdx.x & 3, b = (blockIdx.x >> 2) & 7, ntl = blockIdx.x >> 5;
  const int n0 = ntl * 32;
  const int lane = t & 63, w = t >> 6;
  const int m = lane & 15, quad = lane >> 4;

  const u16* wbase = Wfrag + (size_t)r * 65536 + (size_t)(w * 4) * 8 * 512 + lane * 8;
  const u16* xbase = Xbf + (size_t)(b * Nn + n0 + m) * CIN + quad * 8;

  f32x4 acc[4][2];
#pragma unroll
  for (int ct = 0; ct < 4; ++ct)
#pragma unroll
    for (int nt = 0; nt < 2; ++nt) acc[ct][nt] = (f32x4){0.f, 0.f, 0.f, 0.f};

#pragma unroll
  for (int kc = 0; kc < 8; ++kc) {
    bf16x8 af[4], bfr[2];
#pragma unroll
    for (int ct = 0; ct < 4; ++ct)
      af[ct] = *(const bf16x8*)(wbase + (size_t)(ct * 8 + kc) * 512);
#pragma unroll
    for (int nt = 0; nt < 2; ++nt)
      bfr[nt] = *(const bf16x8*)(xbase + (size_t)(nt * 16) * CIN + kc * 32);
#pragma unroll
    for (int ct = 0; ct < 4; ++ct)
#pragma unroll
      for (int nt = 0; nt < 2; ++nt)
        acc[ct][nt] = __builtin_amdgcn_mfma_f32_16x16x32_bf16(af[ct], bfr[nt], acc[ct][nt], 0, 0, 0);
  }

  // frag-ordered store (slice sl=r*8+b, head h=w); jb fixed per block
  u16* fragbase = fTf + (size_t)(((r * Bsz + b) * 4 + w) * 128) * 512;
  const int jb = n0 >> 5;
  const int e = m & 7;
#pragma unroll
  for (int ct = 0; ct < 4; ++ct) {
#pragma unroll
    for (int nt = 0; nt < 2; ++nt) {
      const int qt = nt * 2 + (m >> 3);
      u16* dst = fragbase + (size_t)((jb * 4 + ct) * 512) + (qt * 16 + quad * 4) * 8 + e;
#pragma unroll
      for (int p = 0; p < 4; ++p) dst[p * 8] = (u16)f2bf(acc[ct][nt][p]);
    }
  }
}

// ---------- attention: r-loop in block, direct out write, barrier-free ----------
// grid 512: b = bid&7 (XCD-pinned -> 2MB fTf/b L2-resident), itile = bid>>3
// (64 tiles of 16 i). block 256 = 4 head-waves. Per wave: r=0..3 sequential,
// per-r normalize, accumulate in registers, single plain store. No LDS.
__global__ __launch_bounds__(256, 4)
void gatt_attn(const unsigned long long* __restrict__ adjm,
               const u16* __restrict__ fTf, const float* __restrict__ Lip,
               const float* __restrict__ Ljp, float* __restrict__ out) {
  const int t = threadIdx.x;
  const int b = blockIdx.x & 7;
  const int i0 = (blockIdx.x >> 3) * 16;
  const int h = t >> 6, lane = t & 63;
  const int m = lane & 15, quad = lane >> 4;
  const int qo = quad * 8;

  bf16x8 ones;
#pragma unroll
  for (int e = 0; e < 8; ++e) ones[e] = (short)0x3F80;

  float outsum[4][4];
#pragma unroll
  for (int nt = 0; nt < 4; ++nt)
#pragma unroll
    for (int p = 0; p < 4; ++p) outsum[nt][p] = 0.f;

  for (int r = 0; r < NR; ++r) {
    const float liv = Lip[((size_t)((r * NH + h) * Bsz + b)) * Nn + i0 + m];
    const float* ljh = Ljp + ((size_t)((r * NH + h) * Bsz + b)) * Nn;
    const unsigned long long* amp = adjm + ((size_t)((b * Nn + i0 + m) * NR + r)) * 16;
    const bf16x8* fp = (const bf16x8*)fTf + (size_t)((r * Bsz + b) * 4 + h) * 8192;

    f32x4 acc[4], den;
    den = (f32x4){0.f, 0.f, 0.f, 0.f};
#pragma unroll
    for (int nt = 0; nt < 4; ++nt) acc[nt] = (f32x4){0.f, 0.f, 0.f, 0.f};

    for (int jq = 0; jq < 16; ++jq) {
      const uint2 mw = *(const uint2*)(amp + jq);
#pragma unroll
      for (int half = 0; half < 2; ++half) {
        const int jb = jq * 2 + half;
        const unsigned mb = (half ? mw.y : mw.x) >> qo;
        const f32x2* lj2p = (const f32x2*)(ljh + jb * 32 + qo);
        bf16x8 bfr[4];
#pragma unroll
        for (int nt = 0; nt < 4; ++nt) bfr[nt] = fp[(jb * 4 + nt) * 64 + lane];
        const f32x2 li2 = {liv, liv};
        unsigned afu[4];
#pragma unroll
        for (int pr = 0; pr < 4; ++pr) {
          const f32x2 s2 = li2 + lj2p[pr];          // v_pk_add_f32
          const f32x2 s02 = s2 * 0.2f;              // v_pk_mul_f32
          const float t0 = fmaxf(s2.x, s02.x);
          const float t1 = fmaxf(s2.y, s02.y);
          const unsigned e0 =
              __float_as_uint(fast_exp2(t0)) & (unsigned)sbfe1(mb, 2 * pr);
          const unsigned e1 =
              __float_as_uint(fast_exp2(t1)) & (unsigned)sbfe1(mb, 2 * pr + 1);
          afu[pr] = perm_hi16(e1, e0);              // v_perm_b32 pack
        }
        union { unsigned u[4]; bf16x8 v; } af;
        af.u[0] = afu[0]; af.u[1] = afu[1]; af.u[2] = afu[2]; af.u[3] = afu[3];
        den = __builtin_amdgcn_mfma_f32_16x16x32_bf16(af.v, ones, den, 0, 0, 0);
#pragma unroll
        for (int nt = 0; nt < 4; ++nt)
          acc[nt] = __builtin_amdgcn_mfma_f32_16x16x32_bf16(af.v, bfr[nt], acc[nt], 0, 0, 0);
      }
    }

#pragma unroll
    for (int p = 0; p < 4; ++p) {
      const float inv = __builtin_amdgcn_rcpf(den[p]);
#pragma unroll
      for (int nt = 0; nt < 4; ++nt) outsum[nt][p] = fmaf(acc[nt][p], inv, outsum[nt][p]);
    }
  }

#pragma unroll
  for (int p = 0; p < 4; ++p) {
    const int i = i0 + quad * 4 + p;
    float* op = out + ((size_t)(b * Nn) + i) * COUT + h * 64 + m;
#pragma unroll
    for (int nt = 0; nt < 4; ++nt) op[nt * 16] = outsum[nt][p];
  }
}

extern "C" void kernel_launch(void* const* d_in, const int* in_sizes, int n_in,
                              void* d_out, int out_size, void* d_ws, size_t ws_size,
                              hipStream_t stream) {
  const float* X = (const float*)d_in[0];
  const int4* adj4 = (const int4*)d_in[1];
  const float* W = (const float*)d_in[2];
  const float* a = (const float*)d_in[3];
  float* out = (float*)d_out;

  char* ws = (char*)d_ws;
  u16* fTf = (u16*)ws;
  float* Lip = (float*)(ws + OFF_LIP);
  float* Ljp = (float*)(ws + OFF_LJP);
  unsigned long long* adjm = (unsigned long long*)(ws + OFF_ADJM);
  u16* Xbf = (u16*)(ws + OFF_XBF);
  u16* Wfrag = (u16*)(ws + OFF_WFRAG);
  float* wa_l = (float*)(ws + OFF_WAL);
  float* wa_r = (float*)(ws + OFF_WAR);

  gatt_packprep<<<dim3(32816), dim3(256), 0, stream>>>(adj4, W, a, adjm, Wfrag,
                                                       wa_l, wa_r);
  gatt_logitx<<<dim3(512), dim3(256), 0, stream>>>(X, (const float4*)wa_l,
                                                   (const float4*)wa_r, Lip, Ljp, Xbf);
  gatt_fgemm<<<dim3(1024), dim3(256), 0, stream>>>(Xbf, Wfrag, fTf);
  gatt_attn<<<dim3(512), dim3(256), 0, stream>>>(adjm, fTf, Lip, Ljp, out);
}

// Round 7
// 296.116 us; speedup vs baseline: 1.0875x; 1.0875x over previous
//
#include <hip/hip_runtime.h>
#include <math.h>

#define Bsz 8
#define Nn 1024
#define CIN 256
#define COUT 256
#define NR 4
#define NH 4

typedef unsigned short u16;
typedef __attribute__((ext_vector_type(8))) short bf16x8;
typedef __attribute__((ext_vector_type(4))) float f32x4;
typedef __attribute__((ext_vector_type(2))) float f32x2;

// ws layout (bytes):
//   fTf  : [sl=r*8+b][h][jb 0..31][nt 0..3][lane] bf16x8  16 MB @ 0
//   Lip  : [combo=r*4+h][b][n] f32 (li*log2e)   512K @ 16M
//   Ljp  : same                                  512K @ 16.5M
//   adjm : [b][i][r][16] u64                     4 MB @ 17M
//   Xbf  : [b*n][k] bf16                         4 MB @ 21M
//   Wfrag: [r][cg 0..15][kc 0..7][lane][e] bf16 (A-frag order) 512K @ 25M
//   wa_l : [combo][k] f32                        16K  @ 25.5M
//   wa_r : [combo][k] f32                        16K  @ +16K
#define OFF_LIP (16u << 20)
#define OFF_LJP ((16u << 20) + (512u << 10))
#define OFF_ADJM (17u << 20)
#define OFF_XBF (21u << 20)
#define OFF_WFRAG (25u << 20)
#define OFF_WAL ((25u << 20) + (512u << 10))
#define OFF_WAR ((25u << 20) + (528u << 10))

#define LOG2E 1.4426950408889634f

__device__ __forceinline__ short f2bf(float x) {
  union { float f; unsigned u; } v; v.f = x;
  unsigned r = (v.u + 0x7FFFu + ((v.u >> 16) & 1u)) >> 16;
  return (short)r;
}

__device__ __forceinline__ float fast_exp2(float x) {
#if __has_builtin(__builtin_amdgcn_exp2f)
  return __builtin_amdgcn_exp2f(x);
#else
  return exp2f(x);
#endif
}

__device__ __forceinline__ int sbfe1(unsigned v, int bit) {
#if __has_builtin(__builtin_amdgcn_sbfe)
  return __builtin_amdgcn_sbfe((int)v, bit, 1);
#else
  return ((int)(v << (31 - bit))) >> 31;
#endif
}

__device__ __forceinline__ unsigned perm_hi16(unsigned hi, unsigned lo) {
#if __has_builtin(__builtin_amdgcn_perm)
  return __builtin_amdgcn_perm(hi, lo, 0x07060302u);
#else
  return (lo >> 16) | (hi & 0xFFFF0000u);
#endif
}

// ---------- pack (bid<32768) + prep: Wfrag (next 32) + wa tables (next 16) ----------
__global__ __launch_bounds__(256, 4)
void gatt_packprep(const int4* __restrict__ adj4, const float* __restrict__ W,
                   const float* __restrict__ a, unsigned long long* __restrict__ adjm,
                   u16* __restrict__ Wfrag, float* __restrict__ wa_l,
                   float* __restrict__ wa_r) {
  const int t = threadIdx.x;
  if (blockIdx.x < 32768) {
    const int wid = blockIdx.x * 4 + (t >> 6);
    const int lane = t & 63;
    const int jw = wid & 15;
    const int i = (wid >> 4) & 1023;
    const int b = wid >> 14;
    const int j = jw * 64 + lane;
    const int4 av = adj4[(size_t)(b * Nn + i) * Nn + j];
    const unsigned long long b0 = __ballot(av.x != 0);
    const unsigned long long b1 = __ballot(av.y != 0);
    const unsigned long long b2 = __ballot(av.z != 0);
    const unsigned long long b3 = __ballot(av.w != 0);
    if (lane < 4) {
      unsigned long long v = (lane == 0) ? b0 : (lane == 1) ? b1 : (lane == 2) ? b2 : b3;
      adjm[((size_t)((b * Nn + i) * NR + lane)) * 16 + jw] = v;
    }
  } else if (blockIdx.x < 32768 + 32) {
    // W -> bf16 in MFMA A-frag order: Wfrag[r][(cg*8+kc)*512 + (quad*16+m)*8 + e]
    const int bid2 = blockIdx.x - 32768;
    const int r = bid2 >> 3, kc = bid2 & 7;
    const int cg = t >> 4, mm = t & 15;
    float wv[32];
#pragma unroll 8
    for (int kk = 0; kk < 32; ++kk)
      wv[kk] = W[(size_t)r * 65536 + (size_t)(kc * 32 + kk) * COUT + t];
    u16* base = Wfrag + (size_t)r * 65536 + (size_t)(cg * 8 + kc) * 512 + mm * 8;
#pragma unroll
    for (int quad = 0; quad < 4; ++quad) {
      u16 pk[8];
#pragma unroll
      for (int e = 0; e < 8; ++e) pk[e] = (u16)f2bf(wv[quad * 8 + e]);
      *(int4*)(base + quad * 128) = *(int4*)pk;
    }
  } else {
    const int cb = blockIdx.x - 32768 - 32;
    const int r = cb >> 2, h = cb & 3;
    float sl = 0.f, sr = 0.f;
    const float* Wp = W + (size_t)r * 65536 + (size_t)t * COUT + h * 64;
    const float* ap = a + r * 512 + h * 128;
#pragma unroll 8
    for (int c = 0; c < 64; ++c) {
      const float wv = Wp[c];
      sl = fmaf(wv, ap[c], sl);
      sr = fmaf(wv, ap[64 + c], sr);
    }
    wa_l[(size_t)cb * CIN + t] = sl;
    wa_r[(size_t)cb * CIN + t] = sr;
  }
}

// ---------- logits (fp32, pre-scaled by log2e) + X->bf16 conversion ----------
__global__ __launch_bounds__(256, 4)
void gatt_logitx(const float* __restrict__ X, const float4* __restrict__ wal4,
                 const float4* __restrict__ war4, float* __restrict__ Lip,
                 float* __restrict__ Ljp, u16* __restrict__ Xbf) {
  __shared__ float Xs[16 * 260];
  const int t = threadIdx.x;
  const int row0 = blockIdx.x * 16;
  {
    const int il = t >> 4, kq = t & 15;
    const float4* xp = (const float4*)(X + (size_t)(row0 + il) * CIN + kq * 16);
    float4 v[4];
    u16 pk[16];
#pragma unroll
    for (int u = 0; u < 4; ++u) {
      v[u] = xp[u];
      pk[u * 4 + 0] = (u16)f2bf(v[u].x);
      pk[u * 4 + 1] = (u16)f2bf(v[u].y);
      pk[u * 4 + 2] = (u16)f2bf(v[u].z);
      pk[u * 4 + 3] = (u16)f2bf(v[u].w);
    }
    float4* dst = (float4*)(Xs + il * 260 + kq * 16);
#pragma unroll
    for (int u = 0; u < 4; ++u) dst[u] = v[u];
    u16* xb = Xbf + (size_t)(row0 + il) * CIN + kq * 16;
    *(int4*)xb = *(int4*)pk;
    *(int4*)(xb + 8) = *(int4*)(pk + 8);
  }
  __syncthreads();
  const int rl = t >> 4, combo = t & 15;
  float li = 0.f, lj = 0.f;
#pragma unroll 8
  for (int k4 = 0; k4 < 64; ++k4) {
    const float4 x4 = *(const float4*)(Xs + rl * 260 + k4 * 4);
    const float4 wl = wal4[combo * 64 + k4];
    const float4 wr = war4[combo * 64 + k4];
    li += x4.x * wl.x + x4.y * wl.y + x4.z * wl.z + x4.w * wl.w;
    lj += x4.x * wr.x + x4.y * wr.y + x4.z * wr.z + x4.w * wr.w;
  }
  const int g = row0 + rl, b = g >> 10, n = g & 1023;
  const size_t idx = ((size_t)(combo * Bsz + b)) * Nn + n;
  Lip[idx] = li * LOG2E;
  Ljp[idx] = lj * LOG2E;
}

// ---------- f GEMM: zero-LDS, zero-barrier MFMA streaming ----------
__global__ __launch_bounds__(256, 4)
void gatt_fgemm(const u16* __restrict__ Xbf, const u16* __restrict__ Wfrag,
                u16* __restrict__ fTf) {
  const int t = threadIdx.x;
  const int r = blockIdx.x & 3, b = (blockIdx.x >> 2) & 7, ntl = blockIdx.x >> 5;
  const int n0 = ntl * 32;
  const int lane = t & 63, w = t >> 6;
  const int m = lane & 15, quad = lane >> 4;

  const u16* wbase = Wfrag + (size_t)r * 65536 + (size_t)(w * 4) * 8 * 512 + lane * 8;
  const u16* xbase = Xbf + (size_t)(b * Nn + n0 + m) * CIN + quad * 8;

  f32x4 acc[4][2];
#pragma unroll
  for (int ct = 0; ct < 4; ++ct)
#pragma unroll
    for (int nt = 0; nt < 2; ++nt) acc[ct][nt] = (f32x4){0.f, 0.f, 0.f, 0.f};

#pragma unroll
  for (int kc = 0; kc < 8; ++kc) {
    bf16x8 af[4], bfr[2];
#pragma unroll
    for (int ct = 0; ct < 4; ++ct)
      af[ct] = *(const bf16x8*)(wbase + (size_t)(ct * 8 + kc) * 512);
#pragma unroll
    for (int nt = 0; nt < 2; ++nt)
      bfr[nt] = *(const bf16x8*)(xbase + (size_t)(nt * 16) * CIN + kc * 32);
#pragma unroll
    for (int ct = 0; ct < 4; ++ct)
#pragma unroll
      for (int nt = 0; nt < 2; ++nt)
        acc[ct][nt] = __builtin_amdgcn_mfma_f32_16x16x32_bf16(af[ct], bfr[nt], acc[ct][nt], 0, 0, 0);
  }

  u16* fragbase = fTf + (size_t)(((r * Bsz + b) * 4 + w) * 128) * 512;
  const int jb = n0 >> 5;
  const int e = m & 7;
#pragma unroll
  for (int ct = 0; ct < 4; ++ct) {
#pragma unroll
    for (int nt = 0; nt < 2; ++nt) {
      const int qt = nt * 2 + (m >> 3);
      u16* dst = fragbase + (size_t)((jb * 4 + ct) * 512) + (qt * 16 + quad * 4) * 8 + e;
#pragma unroll
      for (int p = 0; p < 4; ++p) dst[p * 8] = (u16)f2bf(acc[ct][nt][p]);
    }
  }
}

// ---------- attention: 16-wave block (4r x 2h), 2 A-frags/wave, LDS r-combine ----------
// grid 512: bid&7 = b (XCD-pinned), (bid>>3)&1 = hpair, bid>>4 = itile (32 i).
// Wave w: r = w>>1, hl = w&1, h = hpair*2+hl. Each wave: streaming barrier-free
// (r,h) numerator+denominator for 32 i x 64 c; per-r normalize; scaled tile ->
// LDS; one barrier; 512 threads sum 4 r-tiles and store out coalesced.
__global__ __launch_bounds__(512, 4)
void gatt_attn(const unsigned long long* __restrict__ adjm,
               const u16* __restrict__ fTf, const float* __restrict__ Lip,
               const float* __restrict__ Ljp, float* __restrict__ out) {
  __shared__ float lred[8 * 2184];  // [hl*4+r][32 i][stride 68], tile stride 2184

  const int t = threadIdx.x;
  const int b = blockIdx.x & 7;
  const int hpair = (blockIdx.x >> 3) & 1;
  const int i0 = (blockIdx.x >> 4) * 32;
  const int w = t >> 6, lane = t & 63;
  const int hl = w & 1, r = w >> 1;
  const int h = hpair * 2 + hl;
  const int m = lane & 15, quad = lane >> 4;
  const int qo = quad * 8;

  const float* lipb = Lip + ((size_t)((r * NH + h) * Bsz + b)) * Nn;
  const float li0 = lipb[i0 + m];
  const float li1 = lipb[i0 + 16 + m];
  const float* ljh = Ljp + ((size_t)((r * NH + h) * Bsz + b)) * Nn;
  const unsigned long long* amp0 = adjm + ((size_t)((b * Nn + i0 + m) * NR + r)) * 16;
  const unsigned long long* amp1 = amp0 + (size_t)16 * NR * 16;
  const bf16x8* fp = (const bf16x8*)fTf + (size_t)((r * Bsz + b) * 4 + h) * 8192;

  bf16x8 ones;
#pragma unroll
  for (int e = 0; e < 8; ++e) ones[e] = (short)0x3F80;

  f32x4 acc[2][4], den[2];
#pragma unroll
  for (int iw = 0; iw < 2; ++iw) {
    den[iw] = (f32x4){0.f, 0.f, 0.f, 0.f};
#pragma unroll
    for (int nt = 0; nt < 4; ++nt) acc[iw][nt] = (f32x4){0.f, 0.f, 0.f, 0.f};
  }

  for (int jq = 0; jq < 16; ++jq) {
    const uint2 mw0 = *(const uint2*)(amp0 + jq);
    const uint2 mw1 = *(const uint2*)(amp1 + jq);
#pragma unroll
    for (int half = 0; half < 2; ++half) {
      const int jb = jq * 2 + half;
      const unsigned w0 = half ? mw0.y : mw0.x;
      const unsigned w1 = half ? mw1.y : mw1.x;
      const f32x2* lj2p = (const f32x2*)(ljh + jb * 32 + qo);
      bf16x8 bfr[4];
#pragma unroll
      for (int nt = 0; nt < 4; ++nt) bfr[nt] = fp[(jb * 4 + nt) * 64 + lane];
#pragma unroll
      for (int iw = 0; iw < 2; ++iw) {
        const float liv = iw ? li1 : li0;
        const unsigned mb = (iw ? w1 : w0) >> qo;
        const f32x2 li2 = {liv, liv};
        unsigned afu[4];
#pragma unroll
        for (int pr = 0; pr < 4; ++pr) {
          const f32x2 s2 = li2 + lj2p[pr];          // v_pk_add_f32
          const f32x2 s02 = s2 * 0.2f;              // v_pk_mul_f32
          const float t0 = fmaxf(s2.x, s02.x);
          const float t1 = fmaxf(s2.y, s02.y);
          const unsigned e0 =
              __float_as_uint(fast_exp2(t0)) & (unsigned)sbfe1(mb, 2 * pr);
          const unsigned e1 =
              __float_as_uint(fast_exp2(t1)) & (unsigned)sbfe1(mb, 2 * pr + 1);
          afu[pr] = perm_hi16(e1, e0);              // v_perm_b32 pack
        }
        union { unsigned u[4]; bf16x8 v; } af;
        af.u[0] = afu[0]; af.u[1] = afu[1]; af.u[2] = afu[2]; af.u[3] = afu[3];
        den[iw] = __builtin_amdgcn_mfma_f32_16x16x32_bf16(af.v, ones, den[iw], 0, 0, 0);
#pragma unroll
        for (int nt = 0; nt < 4; ++nt)
          acc[iw][nt] = __builtin_amdgcn_mfma_f32_16x16x32_bf16(af.v, bfr[nt], acc[iw][nt], 0, 0, 0);
      }
    }
  }

  // normalize per r and write scaled tile to LDS (row stride 68: 2-way free)
  float* ltile = lred + (hl * 4 + r) * 2184;
#pragma unroll
  for (int iw = 0; iw < 2; ++iw) {
#pragma unroll
    for (int p = 0; p < 4; ++p) {
      const float inv = __builtin_amdgcn_rcpf(den[iw][p]);
      float* lp = ltile + (iw * 16 + quad * 4 + p) * 68 + m;
#pragma unroll
      for (int nt = 0; nt < 4; ++nt) lp[nt * 16] = acc[iw][nt][p] * inv;
    }
  }
  __syncthreads();

  // combine: thread t sums 4 r-tiles for 8 consecutive c of one i-row
  {
    const int ci = t >> 4;            // i-local 0..31
    const int cc = (t & 15) * 8;      // c-local 0..127 (within h-pair)
    const int chl = cc >> 6;
    const int cin = cc & 63;
    const float* basep = lred + chl * 4 * 2184 + ci * 68 + cin;
    f32x4 s0 = (f32x4){0.f, 0.f, 0.f, 0.f};
    f32x4 s1 = (f32x4){0.f, 0.f, 0.f, 0.f};
#pragma unroll
    for (int rr = 0; rr < 4; ++rr) {
      const f32x4 a0 = *(const f32x4*)(basep + rr * 2184);
      const f32x4 a1 = *(const f32x4*)(basep + rr * 2184 + 4);
      s0 += a0;
      s1 += a1;
    }
    float* op = out + ((size_t)(b * Nn) + i0 + ci) * COUT + hpair * 128 + cc;
    *(f32x4*)op = s0;
    *(f32x4*)(op + 4) = s1;
  }
}

extern "C" void kernel_launch(void* const* d_in, const int* in_sizes, int n_in,
                              void* d_out, int out_size, void* d_ws, size_t ws_size,
                              hipStream_t stream) {
  const float* X = (const float*)d_in[0];
  const int4* adj4 = (const int4*)d_in[1];
  const float* W = (const float*)d_in[2];
  const float* a = (const float*)d_in[3];
  float* out = (float*)d_out;

  char* ws = (char*)d_ws;
  u16* fTf = (u16*)ws;
  float* Lip = (float*)(ws + OFF_LIP);
  float* Ljp = (float*)(ws + OFF_LJP);
  unsigned long long* adjm = (unsigned long long*)(ws + OFF_ADJM);
  u16* Xbf = (u16*)(ws + OFF_XBF);
  u16* Wfrag = (u16*)(ws + OFF_WFRAG);
  float* wa_l = (float*)(ws + OFF_WAL);
  float* wa_r = (float*)(ws + OFF_WAR);

  gatt_packprep<<<dim3(32816), dim3(256), 0, stream>>>(adj4, W, a, adjm, Wfrag,
                                                       wa_l, wa_r);
  gatt_logitx<<<dim3(512), dim3(256), 0, stream>>>(X, (const float4*)wa_l,
                                                   (const float4*)wa_r, Lip, Ljp, Xbf);
  gatt_fgemm<<<dim3(1024), dim3(256), 0, stream>>>(Xbf, Wfrag, fTf);
  gatt_attn<<<dim3(512), dim3(512), 0, stream>>>(adjm, fTf, Lip, Ljp, out);
}